// Round 1
// baseline (63299.261 us; speedup 1.0000x reference)
//
#include <hip/hip_runtime.h>
#include <cstddef>

#define T_LEN 32768
#define HID   300
#define HP    304   // padded row width for x/h buffers
#define HK    320   // padded K for MFMA (10 chunks of 32)
#define KC    10
#define IN_D  500
#define OUT_D 100
#define OUTP  104

typedef _Float16 f16x8 __attribute__((ext_vector_type(8)));
typedef _Float16 f16x4 __attribute__((ext_vector_type(4)));
typedef float    f32x4 __attribute__((ext_vector_type(4)));

// Static device scratch (avoids relying on ws_size)
__device__ __align__(16) float g_x [(size_t)(T_LEN + 4) * HP];
__device__ __align__(16) float g_h0[(size_t)T_LEN * HP];
__device__ __align__(16) float g_h1[(size_t)T_LEN * HP];
__device__ __align__(16) float g_wt0[IN_D * HP];
__device__ __align__(16) float g_wt1[HID * HP];
__device__ __align__(16) float g_wtl[HID * OUTP];

// ---------------- transpose + pad: dst[k][j] = (j<J) ? src[j][k] : 0 ----------------
__global__ void k_transpose(const float* __restrict__ src, int J, int K, int JP, int dst_sel)
{
    float* dst = (dst_sel == 0) ? g_wt0 : (dst_sel == 1) ? g_wt1 : g_wtl;
    int idx = blockIdx.x * 256 + threadIdx.x;
    if (idx >= K * JP) return;
    int k = idx / JP, j = idx - k * JP;
    dst[idx] = (j < J) ? src[j * K + k] : 0.f;
}

// ---------------- x = inp @ WT + (b1+b2), 32 rows per block ----------------
// sel 0: inp = in0 (input_seq, stride S=500), wt = g_wt0
// sel 1: inp = g_h0 (stride S=304),           wt = g_wt1
__global__ __launch_bounds__(320) void k_gemm_in(const float* __restrict__ in0,
                                                 const float* __restrict__ b1,
                                                 const float* __restrict__ b2,
                                                 int S, int K, int sel)
{
    const float* __restrict__ inp = (sel == 0) ? in0 : g_h0;
    const float* __restrict__ wt  = (sel == 0) ? g_wt0 : g_wt1;
    __shared__ float lds[32 * IN_D];
    const int tid = threadIdx.x;
    const int t0  = blockIdx.x * 32;
    {
        const f32x4* src4 = (const f32x4*)(inp + (size_t)t0 * S);
        f32x4* lds4 = (f32x4*)lds;
        const int n4 = (32 * S) >> 2;
        for (int i = tid; i < n4; i += 320) lds4[i] = src4[i];
    }
    __syncthreads();
    const int j = tid;
    if (j >= HP) return;
    float acc[32];
#pragma unroll
    for (int i = 0; i < 32; i++) acc[i] = 0.f;
#pragma unroll 4
    for (int k = 0; k < K; k++) {
        float w = wt[k * HP + j];
#pragma unroll
        for (int i = 0; i < 32; i++) acc[i] += w * lds[i * S + k];  // uniform addr -> LDS broadcast
    }
    const float bias = (j < HID) ? (b1[j] + b2[j]) : 0.f;
#pragma unroll 4
    for (int i = 0; i < 32; i++) g_x[(size_t)(t0 + i) * HP + j] = acc[i] + bias;
}

// ---------------- out = h1 @ WTl + b_lin, 64 rows per block ----------------
__global__ __launch_bounds__(128) void k_gemm_out(const float* __restrict__ blin,
                                                  float* __restrict__ out)
{
    __shared__ float lds[64 * HP];
    const int tid = threadIdx.x;
    const int t0  = blockIdx.x * 64;
    {
        const f32x4* src4 = (const f32x4*)(g_h1 + (size_t)t0 * HP);
        f32x4* lds4 = (f32x4*)lds;
        for (int i = tid; i < (64 * HP) >> 2; i += 128) lds4[i] = src4[i];
    }
    __syncthreads();
    const int j = tid;
    if (j >= OUTP) return;
    float acc[64];
#pragma unroll
    for (int i = 0; i < 64; i++) acc[i] = 0.f;
#pragma unroll 2
    for (int k = 0; k < HID; k++) {
        float w = g_wtl[k * OUTP + j];
#pragma unroll
        for (int i = 0; i < 64; i++) acc[i] += w * lds[i * HP + k];
    }
    if (j < OUT_D) {
        float b = blin[j];
        for (int i = 0; i < 64; i++) out[(size_t)(t0 + i) * OUT_D + j] = acc[i] + b;
    }
}

// ---------------- serial RNN scan: h_t = tanh(x_t + Whh h_{t-1}) ----------------
__device__ __forceinline__ float fast_tanh(float v)
{
    float e = __expf(2.f * v);
    return 1.f - 2.f * __builtin_amdgcn_rcpf(e + 1.f);
}

__global__ __launch_bounds__(512, 1) void k_scan(const float* __restrict__ Whh, int sel)
{
    const float* __restrict__ xin  = g_x;
    float* __restrict__       hout = sel ? g_h1 : g_h0;

    __shared__ __align__(16) _Float16 hlds[2][HK];

    const int tid  = threadIdx.x;
    const int lane = tid & 63;
    const int wave = tid >> 6;       // 0..7
    const int col  = lane & 15;      // MFMA row-within-tile for A, col for D
    const int g    = lane >> 4;      // 0..3 k-group / D row-group

    // zero LDS (incl. pads, so pad garbage never NaN-pollutes)
    for (int i = tid; i < 2 * HK; i += 512) ((_Float16*)hlds)[i] = (_Float16)0.f;

    // 20 tiles of 16 rows over 8 waves: waves get {w, w+8} and waves 0-3 also {w+16}
    const int tA = wave, tB = wave + 8, tC = wave + 16;
    const bool hasC = (wave < 4);
    const int rbA = tA * 16 + g * 4;
    const int rbB = tB * 16 + g * 4;
    const int rbC = tC * 16 + g * 4;

    // Load W_hh as f16 A-fragments. lane holds row = tile*16 + col, k = kc*32 + g*8 + j.
    // Zero for row>=300 or k>=300 so LDS-pad garbage contributes nothing.
    auto loadw = [&](int tile, int kc) -> f16x8 {
        const int row = tile * 16 + col;
        const int kb  = kc * 32 + g * 8;
        f16x8 f;
#pragma unroll
        for (int j = 0; j < 8; j++) {
            const int k = kb + j;
            float wv = (row < HID && k < HID) ? Whh[row * HID + k] : 0.f;
            f[j] = (_Float16)wv;
        }
        return f;
    };
    f16x8 wA[KC], wB[KC], wC[KC];
#pragma unroll
    for (int kc = 0; kc < KC; kc++) {
        wA[kc] = loadw(tA, kc);
        wB[kc] = loadw(tB, kc);
        if (hasC) wC[kc] = loadw(tC, kc);
        else { f16x8 z; 
#pragma unroll
               for (int j = 0; j < 8; j++) z[j] = (_Float16)0.f;
               wC[kc] = z; }
    }

    auto loadx = [&](int t, int rb) -> f32x4 {
        return *(const f32x4*)(xin + (size_t)t * HP + rb);
    };
    f32x4 zero4 = {0.f, 0.f, 0.f, 0.f};
    f32x4 xA0 = loadx(0, rbA), xB0 = loadx(0, rbB), xC0 = hasC ? loadx(0, rbC) : zero4;
    f32x4 xA1 = loadx(1, rbA), xB1 = loadx(1, rbB), xC1 = hasC ? loadx(1, rbC) : zero4;

    __syncthreads();

// epilogue for one tile: y = tanh(acc + x); writer lanes (col==0) publish f16 h to LDS
// buffer (1-R) and fp32 h to global (rows < HP only; tile 19 rows are pure pad).
#define EPI(t_, R_, rb_, acc_, xr_) do {                                          \
        f32x4 y_;                                                                 \
        _Pragma("unroll")                                                         \
        for (int r = 0; r < 4; r++) y_[r] = fast_tanh(acc_[r] + xr_[r]);          \
        if (col == 0) {                                                           \
            f16x4 hv_;                                                            \
            _Pragma("unroll")                                                     \
            for (int r = 0; r < 4; r++) hv_[r] = (_Float16)y_[r];                 \
            *(f16x4*)&hlds[1 - (R_)][rb_] = hv_;                                  \
            if ((rb_) < HP) *(f32x4*)&hout[(size_t)(t_) * HP + (rb_)] = y_;       \
        }                                                                         \
    } while (0)

// one timestep: read h_{t-1} f16 from hlds[R], 10 b128 broadcast reads shared by all
// tiles; issue x-prefetch (t+2) early; MFMA accumulate; epilogue writes hlds[1-R].
#define STEP(t_, R_, xA_, xB_, xC_) do {                                          \
        f16x8 bf[KC];                                                             \
        _Pragma("unroll")                                                         \
        for (int kc = 0; kc < KC; kc++)                                           \
            bf[kc] = *(const f16x8*)&hlds[R_][kc * 32 + g * 8];                   \
        f32x4 nA = loadx((t_) + 2, rbA);                                          \
        f32x4 nB = loadx((t_) + 2, rbB);                                          \
        f32x4 nC = zero4;                                                         \
        if (hasC) nC = loadx((t_) + 2, rbC);                                      \
        f32x4 aA = zero4, aB = zero4, aC = zero4;                                 \
        _Pragma("unroll")                                                         \
        for (int kc = 0; kc < KC; kc++) {                                         \
            aA = __builtin_amdgcn_mfma_f32_16x16x32_f16(wA[kc], bf[kc], aA, 0, 0, 0); \
            aB = __builtin_amdgcn_mfma_f32_16x16x32_f16(wB[kc], bf[kc], aB, 0, 0, 0); \
        }                                                                         \
        if (hasC) {                                                               \
            _Pragma("unroll")                                                     \
            for (int kc = 0; kc < KC; kc++)                                       \
                aC = __builtin_amdgcn_mfma_f32_16x16x32_f16(wC[kc], bf[kc], aC, 0, 0, 0); \
        }                                                                         \
        EPI(t_, R_, rbA, aA, xA_);                                                \
        EPI(t_, R_, rbB, aB, xB_);                                                \
        if (hasC) { EPI(t_, R_, rbC, aC, xC_); }                                  \
        xA_ = nA; xB_ = nB; if (hasC) xC_ = nC;                                   \
    } while (0)

#pragma unroll 1
    for (int t = 0; t < T_LEN; t += 2) {
        STEP(t, 0, xA0, xB0, xC0);
        __syncthreads();
        STEP(t + 1, 1, xA1, xB1, xC1);
        __syncthreads();
    }
#undef STEP
#undef EPI
}

extern "C" void kernel_launch(void* const* d_in, const int* in_sizes, int n_in,
                              void* d_out, int out_size, void* d_ws, size_t ws_size,
                              hipStream_t stream)
{
    (void)in_sizes; (void)n_in; (void)d_ws; (void)ws_size; (void)out_size;
    const float* input = (const float*)d_in[0];
    const float* W_ih0 = (const float*)d_in[1];
    const float* W_hh0 = (const float*)d_in[2];
    const float* b_ih0 = (const float*)d_in[3];
    const float* b_hh0 = (const float*)d_in[4];
    const float* W_ih1 = (const float*)d_in[5];
    const float* W_hh1 = (const float*)d_in[6];
    const float* b_ih1 = (const float*)d_in[7];
    const float* b_hh1 = (const float*)d_in[8];
    const float* W_lin = (const float*)d_in[9];
    const float* b_lin = (const float*)d_in[10];
    float* out = (float*)d_out;

    // weight transposes (pad cols zeroed)
    k_transpose<<<dim3((IN_D * HP + 255) / 256), dim3(256), 0, stream>>>(W_ih0, HID, IN_D, HP, 0);
    k_transpose<<<dim3((HID * HP + 255) / 256), dim3(256), 0, stream>>>(W_ih1, HID, HID, HP, 1);
    k_transpose<<<dim3((HID * OUTP + 255) / 256), dim3(256), 0, stream>>>(W_lin, OUT_D, HID, OUTP, 2);

    // x0 = input @ W_ih0^T + (b_ih0 + b_hh0)
    k_gemm_in<<<dim3(T_LEN / 32), dim3(320), 0, stream>>>(input, b_ih0, b_hh0, IN_D, IN_D, 0);
    // layer-0 scan
    k_scan<<<dim3(1), dim3(512), 0, stream>>>(W_hh0, 0);
    // x1 = h0 @ W_ih1^T + (b_ih1 + b_hh1)
    k_gemm_in<<<dim3(T_LEN / 32), dim3(320), 0, stream>>>(nullptr, b_ih1, b_hh1, HP, HID, 1);
    // layer-1 scan
    k_scan<<<dim3(1), dim3(512), 0, stream>>>(W_hh1, 1);
    // head
    k_gemm_out<<<dim3(T_LEN / 64), dim3(128), 0, stream>>>(b_lin, out);
}

// Round 2
// 47303.375 us; speedup vs baseline: 1.3382x; 1.3382x over previous
//
#include <hip/hip_runtime.h>
#include <cstddef>

#define T_LEN 32768
#define HID   300
#define HP    304   // padded row width for x/h buffers
#define HK    320   // padded K for MFMA (10 chunks of 32)
#define KC    10
#define IN_D  500
#define OUT_D 100
#define OUTP  104
#define DIST  4     // x prefetch distance (steps)

typedef _Float16 f16x8 __attribute__((ext_vector_type(8)));
typedef _Float16 f16x4 __attribute__((ext_vector_type(4)));
typedef float    f32x4 __attribute__((ext_vector_type(4)));

// Static device scratch
__device__ __align__(16) float g_x [(size_t)(T_LEN + DIST) * HP];
__device__ __align__(16) float g_h0[(size_t)T_LEN * HP];
__device__ __align__(16) float g_h1[(size_t)T_LEN * HP];
__device__ __align__(16) float g_wt0[IN_D * HP];
__device__ __align__(16) float g_wt1[HID * HP];
__device__ __align__(16) float g_wtl[HID * OUTP];

// ---------------- transpose + pad: dst[k][j] = (j<J) ? src[j][k] : 0 ----------------
__global__ void k_transpose(const float* __restrict__ src, int J, int K, int JP, int dst_sel)
{
    float* dst = (dst_sel == 0) ? g_wt0 : (dst_sel == 1) ? g_wt1 : g_wtl;
    int idx = blockIdx.x * 256 + threadIdx.x;
    if (idx >= K * JP) return;
    int k = idx / JP, j = idx - k * JP;
    dst[idx] = (j < J) ? src[j * K + k] : 0.f;
}

// ---------------- x = inp @ WT + (b1+b2), 32 rows per block ----------------
__global__ __launch_bounds__(320) void k_gemm_in(const float* __restrict__ in0,
                                                 const float* __restrict__ b1,
                                                 const float* __restrict__ b2,
                                                 int S, int K, int sel)
{
    const float* __restrict__ inp = (sel == 0) ? in0 : g_h0;
    const float* __restrict__ wt  = (sel == 0) ? g_wt0 : g_wt1;
    __shared__ float lds[32 * IN_D];
    const int tid = threadIdx.x;
    const int t0  = blockIdx.x * 32;
    {
        const f32x4* src4 = (const f32x4*)(inp + (size_t)t0 * S);
        f32x4* lds4 = (f32x4*)lds;
        const int n4 = (32 * S) >> 2;
        for (int i = tid; i < n4; i += 320) lds4[i] = src4[i];
    }
    __syncthreads();
    const int j = tid;
    if (j >= HP) return;
    float acc[32];
#pragma unroll
    for (int i = 0; i < 32; i++) acc[i] = 0.f;
#pragma unroll 4
    for (int k = 0; k < K; k++) {
        float w = wt[k * HP + j];
#pragma unroll
        for (int i = 0; i < 32; i++) acc[i] += w * lds[i * S + k];  // uniform addr -> LDS broadcast
    }
    const float bias = (j < HID) ? (b1[j] + b2[j]) : 0.f;
#pragma unroll 4
    for (int i = 0; i < 32; i++) g_x[(size_t)(t0 + i) * HP + j] = acc[i] + bias;
}

// ---------------- out = h1 @ WTl + b_lin, 64 rows per block ----------------
__global__ __launch_bounds__(128) void k_gemm_out(const float* __restrict__ blin,
                                                  float* __restrict__ out)
{
    __shared__ float lds[64 * HP];
    const int tid = threadIdx.x;
    const int t0  = blockIdx.x * 64;
    {
        const f32x4* src4 = (const f32x4*)(g_h1 + (size_t)t0 * HP);
        f32x4* lds4 = (f32x4*)lds;
        for (int i = tid; i < (64 * HP) >> 2; i += 128) lds4[i] = src4[i];
    }
    __syncthreads();
    const int j = tid;
    if (j >= OUTP) return;
    float acc[64];
#pragma unroll
    for (int i = 0; i < 64; i++) acc[i] = 0.f;
#pragma unroll 2
    for (int k = 0; k < HID; k++) {
        float w = g_wtl[k * OUTP + j];
#pragma unroll
        for (int i = 0; i < 64; i++) acc[i] += w * lds[i * HP + k];
    }
    if (j < OUT_D) {
        float b = blin[j];
        for (int i = 0; i < 64; i++) out[(size_t)(t0 + i) * OUT_D + j] = acc[i] + b;
    }
}

// ---------------- serial RNN scan: h_t = tanh(x_t + Whh h_{t-1}) ----------------
__device__ __forceinline__ float fast_tanh(float v)
{
    float e = __expf(2.f * v);
    return 1.f - 2.f * __builtin_amdgcn_rcpf(e + 1.f);
}

// runtime-index-free element select from f32x4 (avoids scratch, rule #20)
__device__ __forceinline__ float sel4(f32x4 a, bool c1, bool c2)
{
    float v01 = c1 ? a[1] : a[0];
    float v23 = c1 ? a[3] : a[2];
    return c2 ? v23 : v01;
}

__global__ __launch_bounds__(512, 1) void k_scan(const float* __restrict__ Whh, int sel)
{
    const float* __restrict__ xin  = g_x;
    float* __restrict__       hout = sel ? g_h1 : g_h0;

    __shared__ __align__(16) _Float16 hlds[2][HK];

    const int tid  = threadIdx.x;
    const int lane = tid & 63;
    const int wave = tid >> 6;       // 0..7
    const int col  = lane & 15;      // MFMA A-row-within-tile / D-col
    const int g    = lane >> 4;      // 0..3 k-group / D row-group
    const int r    = col & 3;        // the acc element this lane finalizes
    const bool c1  = (col & 1) != 0;
    const bool c2  = (col & 2) != 0;
    const bool writer = (col < 4);   // col == r for writers

    // 20 tiles of 16 rows over 8 waves: waves get {w, w+8}; waves 0-3 also {w+16}
    const int tA = wave, tB = wave + 8, tC = wave + 16;
    const bool hasC = (wave < 4);
    const int rowA = tA * 16 + g * 4 + r;   // < 128, always valid
    const int rowB = tB * 16 + g * 4 + r;   // < 256, always valid
    const int rowC = tC * 16 + g * 4 + r;   // up to 319: guard stores vs HP

    // zero both h LDS buffers (incl. pads)
    for (int i = tid; i < 2 * HK; i += 512) ((_Float16*)hlds)[i] = (_Float16)0.f;

    // W_hh as f16 A-fragments: lane holds row = tile*16 + col, k = kc*32 + g*8 + j.
    // Zero rows/k >= 300 so LDS-pad garbage is annihilated.
    auto loadw = [&](int tile, int kc) -> f16x8 {
        const int row = tile * 16 + col;
        const int kb  = kc * 32 + g * 8;
        f16x8 f;
#pragma unroll
        for (int j = 0; j < 8; j++) {
            const int k = kb + j;
            float wv = (row < HID && k < HID) ? Whh[row * HID + k] : 0.f;
            f[j] = (_Float16)wv;
        }
        return f;
    };
    f16x8 wA[KC], wB[KC], wC[KC];
#pragma unroll
    for (int kc = 0; kc < KC; kc++) {
        wA[kc] = loadw(tA, kc);
        wB[kc] = loadw(tB, kc);
        if (hasC) wC[kc] = loadw(tC, kc);
        else {
            f16x8 z;
#pragma unroll
            for (int j = 0; j < 8; j++) z[j] = (_Float16)0.f;
            wC[kc] = z;
        }
    }

    __syncthreads();   // once; LDS zeroed + nothing in flight that matters

    // x prefetch: scalar per lane (the one element it finalizes), 4 static slots
    float xA[4], xB[4], xC[4];
#pragma unroll
    for (int s = 0; s < 4; s++) {
        xA[s] = xin[(size_t)s * HP + rowA];
        xB[s] = xin[(size_t)s * HP + rowB];
        xC[s] = hasC ? xin[(size_t)s * HP + rowC] : 0.f;
    }

    const f32x4 zero4 = {0.f, 0.f, 0.f, 0.f};

// one timestep. bf: 10 broadcast b128 reads of h_{t-1}; issue x loads for t+DIST early;
// 2x5 split MFMA chains per tile; 1 tanh per lane; writer lanes publish f16->LDS[1-R],
// f32->global.
#define STEP(t_, R_, s_) do {                                                          \
        f16x8 bf[KC];                                                                  \
        _Pragma("unroll")                                                              \
        for (int kc = 0; kc < KC; kc++)                                                \
            bf[kc] = *(const f16x8*)&hlds[R_][kc * 32 + g * 8];                        \
        float nxA = xin[(size_t)((t_) + DIST) * HP + rowA];                            \
        float nxB = xin[(size_t)((t_) + DIST) * HP + rowB];                            \
        float nxC = hasC ? xin[(size_t)((t_) + DIST) * HP + rowC] : 0.f;               \
        f32x4 aA0 = zero4, aA1 = zero4, aB0 = zero4, aB1 = zero4;                      \
        f32x4 aC0 = zero4, aC1 = zero4;                                                \
        _Pragma("unroll")                                                              \
        for (int kc = 0; kc < 5; kc++) {                                               \
            aA0 = __builtin_amdgcn_mfma_f32_16x16x32_f16(wA[kc], bf[kc], aA0, 0, 0, 0);\
            aB0 = __builtin_amdgcn_mfma_f32_16x16x32_f16(wB[kc], bf[kc], aB0, 0, 0, 0);\
            if (hasC)                                                                  \
            aC0 = __builtin_amdgcn_mfma_f32_16x16x32_f16(wC[kc], bf[kc], aC0, 0, 0, 0);\
        }                                                                              \
        _Pragma("unroll")                                                              \
        for (int kc = 5; kc < KC; kc++) {                                              \
            aA1 = __builtin_amdgcn_mfma_f32_16x16x32_f16(wA[kc], bf[kc], aA1, 0, 0, 0);\
            aB1 = __builtin_amdgcn_mfma_f32_16x16x32_f16(wB[kc], bf[kc], aB1, 0, 0, 0);\
            if (hasC)                                                                  \
            aC1 = __builtin_amdgcn_mfma_f32_16x16x32_f16(wC[kc], bf[kc], aC1, 0, 0, 0);\
        }                                                                              \
        float sA = sel4(aA0, c1, c2) + sel4(aA1, c1, c2);                              \
        float sB = sel4(aB0, c1, c2) + sel4(aB1, c1, c2);                              \
        float yA = fast_tanh(sA + xA[s_]);                                             \
        float yB = fast_tanh(sB + xB[s_]);                                             \
        float yC = 0.f;                                                                \
        if (hasC) {                                                                    \
            float sC = sel4(aC0, c1, c2) + sel4(aC1, c1, c2);                          \
            yC = fast_tanh(sC + xC[s_]);                                               \
        }                                                                              \
        if (writer) {                                                                  \
            hlds[1 - (R_)][tA * 16 + g * 4 + col] = (_Float16)yA;                      \
            hlds[1 - (R_)][tB * 16 + g * 4 + col] = (_Float16)yB;                      \
            hout[(size_t)(t_) * HP + rowA] = yA;                                       \
            hout[(size_t)(t_) * HP + rowB] = yB;                                       \
            if (hasC) {                                                                \
                hlds[1 - (R_)][tC * 16 + g * 4 + col] = (_Float16)yC;                  \
                if (rowC < HP) hout[(size_t)(t_) * HP + rowC] = yC;                    \
            }                                                                          \
        }                                                                              \
        xA[s_] = nxA; xB[s_] = nxB; xC[s_] = nxC;                                      \
    } while (0)

// raw barrier: LDS ops drained, vmcnt NOT drained (x prefetch stays in flight)
#define BAR() do {                                                                     \
        asm volatile("s_waitcnt lgkmcnt(0)" ::: "memory");                             \
        __builtin_amdgcn_sched_barrier(0);                                             \
        __builtin_amdgcn_s_barrier();                                                  \
        __builtin_amdgcn_sched_barrier(0);                                             \
    } while (0)

#pragma unroll 1
    for (int t0 = 0; t0 < T_LEN; t0 += 4) {
        STEP(t0 + 0, 0, 0); BAR();
        STEP(t0 + 1, 1, 1); BAR();
        STEP(t0 + 2, 0, 2); BAR();
        STEP(t0 + 3, 1, 3); BAR();
    }
#undef STEP
#undef BAR
}

extern "C" void kernel_launch(void* const* d_in, const int* in_sizes, int n_in,
                              void* d_out, int out_size, void* d_ws, size_t ws_size,
                              hipStream_t stream)
{
    (void)in_sizes; (void)n_in; (void)d_ws; (void)ws_size; (void)out_size;
    const float* input = (const float*)d_in[0];
    const float* W_ih0 = (const float*)d_in[1];
    const float* W_hh0 = (const float*)d_in[2];
    const float* b_ih0 = (const float*)d_in[3];
    const float* b_hh0 = (const float*)d_in[4];
    const float* W_ih1 = (const float*)d_in[5];
    const float* W_hh1 = (const float*)d_in[6];
    const float* b_ih1 = (const float*)d_in[7];
    const float* b_hh1 = (const float*)d_in[8];
    const float* W_lin = (const float*)d_in[9];
    const float* b_lin = (const float*)d_in[10];
    float* out = (float*)d_out;

    // weight transposes (pad cols zeroed)
    k_transpose<<<dim3((IN_D * HP + 255) / 256), dim3(256), 0, stream>>>(W_ih0, HID, IN_D, HP, 0);
    k_transpose<<<dim3((HID * HP + 255) / 256), dim3(256), 0, stream>>>(W_ih1, HID, HID, HP, 1);
    k_transpose<<<dim3((HID * OUTP + 255) / 256), dim3(256), 0, stream>>>(W_lin, OUT_D, HID, OUTP, 2);

    // x0 = input @ W_ih0^T + (b_ih0 + b_hh0)
    k_gemm_in<<<dim3(T_LEN / 32), dim3(320), 0, stream>>>(input, b_ih0, b_hh0, IN_D, IN_D, 0);
    // layer-0 scan
    k_scan<<<dim3(1), dim3(512), 0, stream>>>(W_hh0, 0);
    // x1 = h0 @ W_ih1^T + (b_ih1 + b_hh1)
    k_gemm_in<<<dim3(T_LEN / 32), dim3(320), 0, stream>>>(nullptr, b_ih1, b_hh1, HP, HID, 1);
    // layer-1 scan
    k_scan<<<dim3(1), dim3(512), 0, stream>>>(W_hh1, 1);
    // head
    k_gemm_out<<<dim3(T_LEN / 64), dim3(128), 0, stream>>>(b_lin, out);
}